// Round 17
// baseline (303.830 us; speedup 1.0000x reference)
//
#include <hip/hip_runtime.h>
#include <hip/hip_bf16.h>
#include <hip/hip_fp16.h>
#include <cstdint>
#include <cstddef>

#define NPLANE 262144      // 512*512
#define HSTR 144           // H row stride (fp16 elems) = 288B; K padded to 144 exactly
#define PW_LAYER 18432     // shorts per packed layer
#define NCELL 32768        // 15-bit morton cells
#define NSAMP 524288
#define NRAY 4096

// ws layout (bytes)
#define WS_FEAT_OFF 131072
#define FEAT_BYTES  75497472
#define WS_CNT_OFF  (WS_FEAT_OFF + FEAT_BYTES)
#define WS_OFFS_OFF (WS_CNT_OFF + 131072)
#define WS_XS_OFF   (WS_OFFS_OFF + 131072)
#define WS_PED_OFF  (WS_XS_OFF + (size_t)NSAMP*16)
#define WS_END      (WS_PED_OFF + (size_t)NRAY*28*2)

// merged-prepass block ranges: {transpose | prep_weights | ped | scatter}
#define TRS_BLKS 3072
#define PREP_BLKS 216
#define PED_BLKS 16
#define SCAT_BLKS 2048
#define K2_BLKS (TRS_BLKS + PREP_BLKS + PED_BLKS + SCAT_BLKS)

typedef unsigned int uint;
typedef __attribute__((ext_vector_type(16))) float f32x16;
typedef _Float16 half8 __attribute__((ext_vector_type(8)));

__device__ __forceinline__ unsigned short f16u(float f){
    __half h = __float2half(f);
    return *reinterpret_cast<unsigned short*>(&h);
}
__device__ __forceinline__ f32x16 mfma16_(half8 a, half8 b, f32x16 c){
    return __builtin_amdgcn_mfma_f32_32x32x16_f16(a, b, c, 0,0,0);
}

// ---------------- morton key ----------------
__device__ __forceinline__ uint part3(uint v){
    v &= 0x3ff;
    v = (v | (v<<16)) & 0x030000FFu;
    v = (v | (v<<8))  & 0x0300F00Fu;
    v = (v | (v<<4))  & 0x030C30C3u;
    v = (v | (v<<2))  & 0x09249249u;
    return v;
}
__device__ __forceinline__ uint cellkey(float x0, float x1, float x2){
    const float s = 1.0f/3.0f;
    const int cx = min(max((int)((x0*s+1.0f)*16.0f),0),31);
    const int cy = min(max((int)((x1*s+1.0f)*16.0f),0),31);
    const int cz = min(max((int)((x2*s+1.0f)*16.0f),0),31);
    return part3((uint)cx) | (part3((uint)cy)<<1) | (part3((uint)cz)<<2);
}

// ---------------- K1: histogram ----------------
__global__ __launch_bounds__(256) void hist_k(const float* __restrict__ x, uint* __restrict__ counts){
    const int i = blockIdx.x*256 + threadIdx.x;
    if (i >= NSAMP) return;
    atomicAdd(&counts[cellkey(x[3*i], x[3*i+1], x[3*i+2])], 1u);
}

// ---------------- K2: scan (1 block, 1024 threads) ----------------
__global__ __launch_bounds__(1024) void scan_k(const uint* __restrict__ counts, uint* __restrict__ offs){
    __shared__ uint ps[1024];
    const int t = threadIdx.x;
    uint loc[32]; uint s = 0;
    #pragma unroll
    for (int i=0;i<32;++i){ loc[i] = counts[t*32+i]; s += loc[i]; }
    ps[t] = s; __syncthreads();
    for (int off=1; off<1024; off<<=1){
        uint v = (t>=off) ? ps[t-off] : 0u;
        __syncthreads();
        ps[t] += v;
        __syncthreads();
    }
    uint base = ps[t] - s;     // exclusive prefix
    #pragma unroll
    for (int i=0;i<32;++i){ offs[t*32+i] = base; base += loc[i]; }
}

// ---------------- K3: merged {transpose | prep_weights | PE(d) table | scatter} ----------------
__global__ __launch_bounds__(256) void prepass_k(const float* __restrict__ feat,
                                                 const float* __restrict__ W0,
                                                 const float* __restrict__ W1,
                                                 const float* __restrict__ W2,
                                                 const float* __restrict__ b0,
                                                 const float* __restrict__ b1,
                                                 const float* __restrict__ b2,
                                                 const float* __restrict__ d,
                                                 const float* __restrict__ x,
                                                 uint* __restrict__ offs,
                                                 unsigned short* __restrict__ featT,
                                                 unsigned short* __restrict__ wp,
                                                 unsigned short* __restrict__ ped,
                                                 float4* __restrict__ xs){
    const int bid = blockIdx.x, tid = threadIdx.x;
    if (bid < TRS_BLKS){
        // ---- transpose feat (3,48,512,512) fp32 -> (3,512,512,48) fp16 ----
        __shared__ unsigned short lb[256*50];
        const int pos = bid*256 + tid;
        const int p  = pos >> 18;
        const int yx = pos & (NPLANE-1);
        const float* src = feat + (size_t)p*48*NPLANE + yx;
        #pragma unroll 4
        for (int c = 0; c < 48; ++c){
            lb[tid*50 + c] = f16u(src[(size_t)c*NPLANE]);
        }
        __syncthreads();
        uint4* dst = (uint4*)(featT + (size_t)bid*(256*48));
        #pragma unroll
        for (int m = 0; m < 6; ++m){
            const int u4 = tid + m*256;
            const int byteoff = u4*16;
            const int smp = byteoff/96;
            const int off = (byteoff%96) >> 2;
            const uint* rw = (const uint*)(lb + smp*50);
            uint4 val; val.x = rw[off]; val.y = rw[off+1]; val.z = rw[off+2]; val.w = rw[off+3];
            dst[u4] = val;
        }
        return;
    }
    if (bid < TRS_BLKS + PREP_BLKS){
        // ---- weights -> fragment-packed fp16, bias folded as row K ----
        const int idx = (bid - TRS_BLKS)*256 + tid;
        if (idx >= 3*PW_LAYER) return;
        const int L = idx / PW_LAYER, base = idx % PW_LAYER;
        const float* W = (L==0)? W0 : (L==1)? W1 : W2;
        const float* B = (L==0)? b0 : (L==1)? b1 : b2;
        const int KREAL = (L==0)? 138 : 128;
        const int e  = base & 7;
        const int l  = (base >> 3) & 63;
        const int fr = base >> 9;
        const int ks = fr >> 2, nt = fr & 3;
        const int k  = ks*16 + (l >> 5)*8 + e;
        const int n  = nt*32 + (l & 31);
        float v = 0.f;
        if (k < KREAL) v = W[k*128 + n];
        else if (k == KREAL) v = B[n];
        wp[idx] = f16u(v);
        return;
    }
    if (bid < TRS_BLKS + PREP_BLKS + PED_BLKS){
        // ---- PE(d) table: ray -> 27 fp16 (stride 28) ----
        const int ray = (bid - TRS_BLKS - PREP_BLKS)*256 + tid;
        if (ray >= NRAY) return;
        const float dv0 = d[ray*3], dv1 = d[ray*3+1], dv2 = d[ray*3+2];
        unsigned short* row = ped + ray*28;
        row[0]=f16u(dv0); row[1]=f16u(dv1); row[2]=f16u(dv2);
        #pragma unroll
        for (int l=0;l<4;++l){
            const float sc = (float)(1<<l);
            float sv, cv;
            __sincosf(dv0*sc, &sv, &cv); row[3+l*6+0]=f16u(sv); row[3+l*6+3]=f16u(cv);
            __sincosf(dv1*sc, &sv, &cv); row[3+l*6+1]=f16u(sv); row[3+l*6+4]=f16u(cv);
            __sincosf(dv2*sc, &sv, &cv); row[3+l*6+2]=f16u(sv); row[3+l*6+5]=f16u(cv);
        }
        row[27] = 0;
        return;
    }
    {
        // ---- scatter (hidden under transpose) ----
        const int i = (bid - TRS_BLKS - PREP_BLKS - PED_BLKS)*256 + tid;
        if (i >= NSAMP) return;
        const float x0 = x[3*i], x1 = x[3*i+1], x2 = x[3*i+2];
        const uint pos = atomicAdd(&offs[cellkey(x0,x1,x2)], 1u);
        xs[pos] = make_float4(x0, x1, x2, __int_as_float(i));
    }
}

// ---- N-split/4 MLP layer: wave w computes cols [w*32, w*32+32) for ALL 64 samples ----
__device__ __forceinline__ void run_layer_ns4(unsigned short* H, const unsigned short* __restrict__ Wp,
                                              int lane, int ln31, int kg, int wid, const int* pr){
    const unsigned short* Hrow0 = H + ln31*HSTR;
    const unsigned short* Hrow1 = H + (32+ln31)*HSTR;
    f32x16 acc0=(f32x16)0.f, acc1=(f32x16)0.f;
    // chunk A: ks 0..4
    {
        half8 bf[5];
        #pragma unroll
        for (int i=0;i<5;++i)
            bf[i] = *reinterpret_cast<const half8*>(Wp + (((i*4+wid)*64 + lane) << 3));
        #pragma unroll
        for (int ks=0; ks<5; ++ks){
            const half8 a0 = *reinterpret_cast<const half8*>(Hrow0 + ks*16 + kg*8);
            const half8 a1 = *reinterpret_cast<const half8*>(Hrow1 + ks*16 + kg*8);
            acc0 = mfma16_(a0, bf[ks], acc0);
            acc1 = mfma16_(a1, bf[ks], acc1);
        }
    }
    // chunk B: ks 5..8
    {
        half8 bf[4];
        #pragma unroll
        for (int i=0;i<4;++i)
            bf[i] = *reinterpret_cast<const half8*>(Wp + ((((5+i)*4+wid)*64 + lane) << 3));
        #pragma unroll
        for (int ks=5; ks<9; ++ks){
            const half8 a0 = *reinterpret_cast<const half8*>(Hrow0 + ks*16 + kg*8);
            const half8 a1 = *reinterpret_cast<const half8*>(Hrow1 + ks*16 + kg*8);
            acc0 = mfma16_(a0, bf[ks-5], acc0);
            acc1 = mfma16_(a1, bf[ks-5], acc1);
        }
    }
    __syncthreads();   // all waves done reading H
    #pragma unroll
    for (int r=0;r<16;++r){
        const int row = pr[r] >> 8;
        const int col = wid*32 + (pr[r] & 255);
        H[row*HSTR + col]      = f16u(fmaxf(acc0[r], 0.f));
        H[(row+32)*HSTR + col] = f16u(fmaxf(acc1[r], 0.f));
    }
    __syncthreads();   // writes visible before next layer reads
}

// ---------------- K4: fused kernel, 4 waves cooperating on 64 sorted samples ----------------
__global__ __launch_bounds__(256, 6) void nerf_mfma(
    const unsigned short* __restrict__ featT,
    const unsigned short* __restrict__ wp0, const unsigned short* __restrict__ wp1,
    const unsigned short* __restrict__ wp2,
    const float* __restrict__ W3, const float* __restrict__ b3,
    const float4* __restrict__ xs, const unsigned short* __restrict__ ped,
    float* __restrict__ out)
{
    __shared__ unsigned short H[64*HSTR];    // 18432 B, shared across 4 waves
    __shared__ uint sBuf[256];               // 1024 B overlay: sX positions -> W3 fp16 pairs
    __shared__ uint sSid[64];                // 256 B  -> total 19712 B (8 blocks/CU w/ reserve)

    const int tid  = threadIdx.x;
    const int wid  = tid >> 6, lane = tid & 63;
    const int ln31 = lane & 31, kg = lane >> 5;
    const int gbase = (((int)blockIdx.x & 7)*1024 + ((int)blockIdx.x >> 3))*64;  // XCD-contiguous
    float4* sX = (float4*)sBuf;              // valid until post-gather barrier

    // ---- layout probes (register-only, f16 MFMA; all waves identical) ----
    half8 pa = (half8)0, pb = (half8)0, qa = (half8)0, qb = (half8)0;
    if (kg == 0){
        pa[0] = (_Float16)(float)ln31;
        pb[0] = (_Float16)1.0f;
        qa[0] = (_Float16)1.0f;
        qb[0] = (_Float16)(float)ln31;
    }
    const f32x16 zz = (f32x16)0.f;
    const f32x16 D1 = mfma16_(pa, pb, zz);
    const f32x16 D2 = mfma16_(qa, qb, zz);
    int pr[16];
    #pragma unroll
    for (int r=0;r<16;++r) pr[r] = (((int)D1[r]) << 8) | (int)D2[r];

    // ---- stage sample records (positions + sid) ----
    if (tid < 64){
        const float4 r = xs[gbase + tid];
        sX[tid] = r;
        sSid[tid] = (uint)__float_as_int(r.w);
    }
    __syncthreads();   // sX/sSid visible to all waves

    // ---- PE(x,10): 192 units (sample, component) over 256 threads ----
    if (tid < 192){
        const int s32 = tid & 63, m = tid >> 6;   // m in 0..2
        const float4 xr = sX[s32];
        const float xn = ((m==0)? xr.x : (m==1)? xr.y : xr.z) * (1.0f/3.0f);
        unsigned short* row = H + s32*HSTR;
        row[75+m] = f16u(xn);
        float sv, cv;
        __sincosf(xn, &sv, &cv);
        #pragma unroll
        for (int l=0;l<10;++l){
            row[78+l*6+m]   = f16u(sv);
            row[78+l*6+3+m] = f16u(cv);
            const float s2v = 2.0f*sv*cv;
            const float c2v = 1.0f - 2.0f*sv*sv;
            sv = s2v; cv = c2v;
        }
    }

    // ---- PE(d): 128 units (sample, half) ----
    if (tid < 128){
        const int s32 = tid >> 1, hf = tid & 1;
        const int sid = (int)sSid[s32];
        const uint* src = (const uint*)(ped + (sid >> 7)*28) + hf*7;
        uint* dstu = (uint*)(H + s32*HSTR + 48) + hf*7;
        if (hf == 0){
            #pragma unroll
            for (int i=0;i<7;++i) dstu[i] = src[i];
        } else {
            #pragma unroll
            for (int i=0;i<6;++i) dstu[i] = src[i];
            H[s32*HSTR + 74] = ((const unsigned short*)src)[12];
        }
    }

    // pad cols 138..143: col138 = fp16 1.0 (bias slot for L0), rest 0
    if (tid < 64){
        *(uint*)(H + tid*HSTR + 138)  = 0x00003C00u;
        *(uint2*)(H + tid*HSTR + 140) = make_uint2(0u, 0u);
    }

    // ---- gather -> cols [0..47]; 384 units over 256 threads (1.5 rounds) ----
    #pragma unroll
    for (int rr=0; rr<2; ++rr){
        const int u = rr*256 + tid;
        if (rr == 1 && tid >= 128) break;     // units 0..383
        const int s32 = u/6, ch = u - s32*6;
        const float4 xr = sX[s32];
        const float xn0 = xr.x*(1.0f/3.0f);
        const float xn1 = xr.y*(1.0f/3.0f);
        const float xn2 = xr.z*(1.0f/3.0f);
        const int c0 = ch*8;
        __half2 acc[4];
        #pragma unroll
        for (int q=0;q<4;++q) acc[q] = __float2half2_rn(0.f);
        #pragma unroll
        for (int p=0;p<3;++p){
            const float gx = (p==1)? xn1 : xn0;
            const float gy = (p==0)? xn1 : xn2;
            const float ix = ((gx+1.0f)*0.5f)*511.0f;
            const float iy = ((gy+1.0f)*0.5f)*511.0f;
            const float fx0 = floorf(ix), fy0 = floorf(iy);
            const float wx1 = ix - fx0, wy1 = iy - fy0;
            const float wx0 = 1.0f-wx1, wy0 = 1.0f-wy1;
            const int x0i = (int)fx0, y0i = (int)fy0;
            const int x0c = min(max(x0i,0),511),   x1c = min(max(x0i+1,0),511);
            const int y0c = min(max(y0i,0),511),   y1c = min(max(y0i+1,0),511);
            const uint r0 = (uint)(p*NPLANE + y0c*512);
            const uint r1 = (uint)(p*NPLANE + y1c*512);
            const uint  av[4] = {(r0+x0c)*48u, (r0+x1c)*48u, (r1+x0c)*48u, (r1+x1c)*48u};
            const float wv[4] = {wx0*wy0, wx1*wy0, wx0*wy1, wx1*wy1};
            #pragma unroll
            for (int cr=0;cr<4;++cr){
                const uint4 uv = *(const uint4*)(featT + av[cr] + c0);
                const __half2 w2 = __float2half2_rn(wv[cr]);
                union { uint4 v; __half2 h[4]; } t; t.v = uv;
                acc[0] = __hfma2(t.h[0], w2, acc[0]);
                acc[1] = __hfma2(t.h[1], w2, acc[1]);
                acc[2] = __hfma2(t.h[2], w2, acc[2]);
                acc[3] = __hfma2(t.h[3], w2, acc[3]);
            }
        }
        union { __half2 h[4]; uint4 v; } pk;
        #pragma unroll
        for (int q=0;q<4;++q) pk.h[q] = acc[q];
        *(uint4*)(H + s32*HSTR + c0) = pk.v;
    }
    __syncthreads();   // H fully built; sX positions now dead

    // ---- overlay: stage W3 fp16 pairs into sBuf (visible via MLP barriers) ----
    {
        const int k = tid >> 1, c = tid & 1;
        sBuf[tid] = ((uint)f16u(W3[k*4 + 2*c])) | (((uint)f16u(W3[k*4 + 2*c + 1])) << 16);
    }

    // ---- MLP: N-split/4 layers ----
    run_layer_ns4(H, wp0, lane, ln31, kg, wid, pr);
    // pad rewrite for L1/L2 bias slot: cols 128..143 <- [1, 0...], rows 0..63 over 128 threads
    if (tid < 128){
        const int row = tid & 63, hf = tid >> 6;
        if (hf == 0) *(uint4*)(H + row*HSTR + 128) = make_uint4(0x00003C00u,0u,0u,0u);
        else         *(uint4*)(H + row*HSTR + 136) = make_uint4(0u,0u,0u,0u);
    }
    __syncthreads();
    run_layer_ns4(H, wp1, lane, ln31, kg, wid, pr);
    run_layer_ns4(H, wp2, lane, ln31, kg, wid, pr);

    // ---- final layer 128->4 (fp16 W3 pairs from LDS); 128 units ----
    if (tid < 128){
        const int s32 = tid >> 1, cp = tid & 1;
        const unsigned short* hrow = H + s32*HSTR;
        const int sid = (int)sSid[s32];
        const int jp = 2*cp;
        const float2 b3v = *(const float2*)(b3 + jp);
        float a0 = b3v.x, a1 = b3v.y;
        #pragma unroll
        for (int q=0;q<16;++q){
            union { uint4 v; __half2 h[4]; } u;
            u.v = *(const uint4*)(hrow + q*8);
            const int k = q*8;
            #pragma unroll
            for (int j2=0;j2<4;++j2){
                const float2 f = __half22float2(u.h[j2]);
                const int k2 = k + j2*2;
                union { uint u32; __half2 h; } w0c, w1c;
                w0c.u32 = sBuf[(k2+0)*2+cp];
                w1c.u32 = sBuf[(k2+1)*2+cp];
                const float2 w0f = __half22float2(w0c.h);
                const float2 w1f = __half22float2(w1c.h);
                a0 += f.x*w0f.x + f.y*w1f.x;
                a1 += f.x*w0f.y + f.y*w1f.y;
            }
        }
        if (cp == 1) a1 = fmaxf(a1, 0.f);
        float2 o; o.x = a0; o.y = a1;
        *(float2*)(out + (size_t)sid*4 + jp) = o;
    }
}

// ================= fallback (round-2 kernel, channel-major gather, fp32 MLP) =================
#define STR 148
#define SBLK 64
template<int K4, int KTAIL>
__device__ __forceinline__ void mlp_layer_fb(float (*Hs)[STR], const float* __restrict__ W,
                                             const float* __restrict__ B, int tid){
    const int tx = tid & 31, ty = tid >> 5;
    const int s0 = ty*8, j0 = tx*4;
    float acc[8][4];
    #pragma unroll
    for (int i=0;i<8;++i){ acc[i][0]=0.f; acc[i][1]=0.f; acc[i][2]=0.f; acc[i][3]=0.f; }
    for (int kk = 0; kk < K4; ++kk){
        const int k = kk*4;
        const float4 wa = *(const float4*)(W + (size_t)(k+0)*128 + j0);
        const float4 wb = *(const float4*)(W + (size_t)(k+1)*128 + j0);
        const float4 wc = *(const float4*)(W + (size_t)(k+2)*128 + j0);
        const float4 wd = *(const float4*)(W + (size_t)(k+3)*128 + j0);
        #pragma unroll
        for (int i=0;i<8;++i){
            const float4 h = *(const float4*)&Hs[s0+i][k];
            acc[i][0] += h.x*wa.x + h.y*wb.x + h.z*wc.x + h.w*wd.x;
            acc[i][1] += h.x*wa.y + h.y*wb.y + h.z*wc.y + h.w*wd.y;
            acc[i][2] += h.x*wa.z + h.y*wb.z + h.z*wc.z + h.w*wd.z;
            acc[i][3] += h.x*wa.w + h.y*wb.w + h.z*wc.w + h.w*wd.w;
        }
    }
    #pragma unroll
    for (int t=0;t<KTAIL;++t){
        const int k = K4*4+t;
        const float4 wa = *(const float4*)(W + (size_t)k*128 + j0);
        #pragma unroll
        for (int i=0;i<8;++i){
            const float h = Hs[s0+i][k];
            acc[i][0] += h*wa.x; acc[i][1] += h*wa.y; acc[i][2] += h*wa.z; acc[i][3] += h*wa.w;
        }
    }
    const float4 bb = *(const float4*)(B + j0);
    __syncthreads();
    #pragma unroll
    for (int i=0;i<8;++i){
        float4 o;
        o.x = fmaxf(acc[i][0]+bb.x, 0.f);
        o.y = fmaxf(acc[i][1]+bb.y, 0.f);
        o.z = fmaxf(acc[i][2]+bb.z, 0.f);
        o.w = fmaxf(acc[i][3]+bb.w, 0.f);
        *(float4*)&Hs[s0+i][j0] = o;
    }
    __syncthreads();
}

__global__ __launch_bounds__(256) void nerf_fused_fb(
    const float* __restrict__ x, const float* __restrict__ d,
    const float* __restrict__ feat,
    const float* __restrict__ W0, const float* __restrict__ b0,
    const float* __restrict__ W1, const float* __restrict__ b1,
    const float* __restrict__ W2, const float* __restrict__ b2,
    const float* __restrict__ W3, const float* __restrict__ b3,
    float* __restrict__ out)
{
    __shared__ float Hs[SBLK][STR];
    __shared__ uint4  sA[3][SBLK];
    __shared__ float4 sW[3][SBLK];

    const int tid = threadIdx.x;
    const int g0 = blockIdx.x * SBLK;

    if (tid < 192){
        const int s = tid & 63, p = tid >> 6;
        const int g = g0 + s;
        const float xn0 = x[3*g+0]/3.0f, xn1 = x[3*g+1]/3.0f, xn2 = x[3*g+2]/3.0f;
        const float gx = (p==1)? xn1 : xn0;
        const float gy = (p==0)? xn1 : xn2;
        const float ix = ((gx+1.0f)*0.5f)*511.0f;
        const float iy = ((gy+1.0f)*0.5f)*511.0f;
        const float fx0 = floorf(ix), fy0 = floorf(iy);
        const float wx1 = ix - fx0, wy1 = iy - fy0;
        const float wx0 = 1.0f-wx1, wy0 = 1.0f-wy1;
        const int x0i = (int)fx0, y0i = (int)fy0;
        const int x0c = min(max(x0i,0),511),   x1c = min(max(x0i+1,0),511);
        const int y0c = min(max(y0i,0),511),   y1c = min(max(y0i+1,0),511);
        const uint bp = (uint)p*48u*NPLANE;
        sA[p][s] = make_uint4(bp + y0c*512 + x0c, bp + y0c*512 + x1c,
                              bp + y1c*512 + x0c, bp + y1c*512 + x1c);
        sW[p][s] = make_float4(wx0*wy0, wx1*wy0, wx0*wy1, wx1*wy1);
    }
    if (tid < 64){
        const int s = tid, g = g0 + s;
        float xn[3];
        xn[0]=x[3*g+0]/3.0f; xn[1]=x[3*g+1]/3.0f; xn[2]=x[3*g+2]/3.0f;
        Hs[s][75]=xn[0]; Hs[s][76]=xn[1]; Hs[s][77]=xn[2];
        float f = 1.0f;
        for (int l=0;l<10;++l){
            #pragma unroll
            for (int m=0;m<3;++m){
                const float a = xn[m]*f;
                Hs[s][78+l*6+m]   = sinf(a);
                Hs[s][78+l*6+3+m] = cosf(a);
            }
            f *= 2.0f;
        }
    } else if (tid < 91){
        const int k = tid-64;
        const int ray = g0 >> 7;
        float v;
        if (k < 3) v = d[ray*3+k];
        else {
            const int l=(k-3)/6, r=(k-3)%6;
            const float a = d[ray*3 + (r%3)] * (float)(1<<l);
            v = (r<3)? sinf(a) : cosf(a);
        }
        for (int s2=0;s2<64;++s2) Hs[s2][48+k]=v;
    }
    __syncthreads();

    for (int it = tid; it < 384; it += 256){
        const int s = it & 63;
        const int c0 = (it >> 6)*8;
        float acc[8];
        #pragma unroll
        for (int q=0;q<8;++q) acc[q]=0.f;
        #pragma unroll
        for (int p=0;p<3;++p){
            const uint4  aa = sA[p][s];
            const float4 ww = sW[p][s];
            const uint  av[4] = {aa.x,aa.y,aa.z,aa.w};
            const float wv[4] = {ww.x,ww.y,ww.z,ww.w};
            #pragma unroll
            for (int cr=0;cr<4;++cr){
                const float w = wv[cr];
                const float* bsrc = feat + av[cr] + (size_t)c0*NPLANE;
                #pragma unroll
                for (int q=0;q<8;++q) acc[q] += w*bsrc[(size_t)q*NPLANE];
            }
        }
        *(float4*)&Hs[s][c0]   = make_float4(acc[0],acc[1],acc[2],acc[3]);
        *(float4*)&Hs[s][c0+4] = make_float4(acc[4],acc[5],acc[6],acc[7]);
    }
    __syncthreads();

    mlp_layer_fb<34,2>(Hs, W0, b0, tid);
    mlp_layer_fb<32,0>(Hs, W1, b1, tid);
    mlp_layer_fb<32,0>(Hs, W2, b2, tid);

    {
        const int s = tid>>2, j = tid&3;
        float acc = 0.f;
        for (int kk=0; kk<32; ++kk){
            const float4 h = *(const float4*)&Hs[s][kk*4];
            const int k = kk*4;
            acc += h.x*W3[(k+0)*4+j] + h.y*W3[(k+1)*4+j]
                 + h.z*W3[(k+2)*4+j] + h.w*W3[(k+3)*4+j];
        }
        acc += b3[j];
        if (j==3) acc = fmaxf(acc, 0.f);
        out[(size_t)blockIdx.x*256 + tid] = acc;
    }
}

extern "C" void kernel_launch(void* const* d_in, const int* in_sizes, int n_in,
                              void* d_out, int out_size, void* d_ws, size_t ws_size,
                              hipStream_t stream){
    (void)in_sizes; (void)n_in; (void)out_size;
    const float* x    = (const float*)d_in[0];
    const float* ddir = (const float*)d_in[1];
    const float* feat = (const float*)d_in[2];
    const float* W0 = (const float*)d_in[3];  const float* b0 = (const float*)d_in[4];
    const float* W1 = (const float*)d_in[5];  const float* b1 = (const float*)d_in[6];
    const float* W2 = (const float*)d_in[7];  const float* b2 = (const float*)d_in[8];
    const float* W3 = (const float*)d_in[9];  const float* b3 = (const float*)d_in[10];
    float* out = (float*)d_out;

    char* wsb = (char*)d_ws;

    if (ws_size >= WS_END){
        unsigned short* wsu   = (unsigned short*)wsb;
        unsigned short* featT = (unsigned short*)(wsb + WS_FEAT_OFF);
        uint*   counts = (uint*)(wsb + WS_CNT_OFF);
        uint*   offs   = (uint*)(wsb + WS_OFFS_OFF);
        float4* xsrec  = (float4*)(wsb + WS_XS_OFF);
        unsigned short* ped = (unsigned short*)(wsb + WS_PED_OFF);
        hipMemsetAsync(counts, 0, NCELL*sizeof(uint), stream);
        hist_k<<<2048, 256, 0, stream>>>(x, counts);
        scan_k<<<1, 1024, 0, stream>>>(counts, offs);
        prepass_k<<<K2_BLKS, 256, 0, stream>>>(feat, W0, W1, W2, b0, b1, b2, ddir, x,
                                               offs, featT, wsu, ped, xsrec);
        nerf_mfma<<<8192, 256, 0, stream>>>(featT,
                                            wsu, wsu + PW_LAYER, wsu + 2*PW_LAYER,
                                            W3, b3, xsrec, ped, out);
    } else {
        nerf_fused_fb<<<8192, 256, 0, stream>>>(x, ddir, feat,
                                                W0,b0,W1,b1,W2,b2,W3,b3, out);
    }
}

// Round 18
// 241.596 us; speedup vs baseline: 1.2576x; 1.2576x over previous
//
#include <hip/hip_runtime.h>
#include <hip/hip_bf16.h>
#include <hip/hip_fp16.h>
#include <cstdint>
#include <cstddef>

#define NPLANE 262144      // 512*512
#define HSTR 144           // H row stride (fp16 elems) = 288B; K padded to 144 exactly
#define PW_LAYER 18432     // shorts per packed layer
#define NCELL 32768        // 15-bit morton cells
#define NSAMP 524288
#define NRAY 4096

// ws layout (bytes)
#define WS_FEAT_OFF 131072
#define FEAT_BYTES  75497472
#define WS_CNT_OFF  (WS_FEAT_OFF + FEAT_BYTES)
#define WS_OFFS_OFF (WS_CNT_OFF + 131072)
#define WS_XS_OFF   (WS_OFFS_OFF + 131072)
#define WS_PED_OFF  (WS_XS_OFF + (size_t)NSAMP*16)
#define WS_END      (WS_PED_OFF + (size_t)NRAY*28*2)

// merged-prepass block ranges: {transpose | prep_weights | ped | scatter}
#define TRS_BLKS 3072
#define PREP_BLKS 216
#define PED_BLKS 16
#define SCAT_BLKS 2048
#define K2_BLKS (TRS_BLKS + PREP_BLKS + PED_BLKS + SCAT_BLKS)

typedef unsigned int uint;
typedef __attribute__((ext_vector_type(16))) float f32x16;
typedef _Float16 half8 __attribute__((ext_vector_type(8)));

__device__ __forceinline__ unsigned short f16u(float f){
    __half h = __float2half(f);
    return *reinterpret_cast<unsigned short*>(&h);
}
__device__ __forceinline__ f32x16 mfma16_(half8 a, half8 b, f32x16 c){
    return __builtin_amdgcn_mfma_f32_32x32x16_f16(a, b, c, 0,0,0);
}

// ---------------- morton key ----------------
__device__ __forceinline__ uint part3(uint v){
    v &= 0x3ff;
    v = (v | (v<<16)) & 0x030000FFu;
    v = (v | (v<<8))  & 0x0300F00Fu;
    v = (v | (v<<4))  & 0x030C30C3u;
    v = (v | (v<<2))  & 0x09249249u;
    return v;
}
__device__ __forceinline__ uint cellkey(float x0, float x1, float x2){
    const float s = 1.0f/3.0f;
    const int cx = min(max((int)((x0*s+1.0f)*16.0f),0),31);
    const int cy = min(max((int)((x1*s+1.0f)*16.0f),0),31);
    const int cz = min(max((int)((x2*s+1.0f)*16.0f),0),31);
    return part3((uint)cx) | (part3((uint)cy)<<1) | (part3((uint)cz)<<2);
}

// ---------------- K1: histogram ----------------
__global__ __launch_bounds__(256) void hist_k(const float* __restrict__ x, uint* __restrict__ counts){
    const int i = blockIdx.x*256 + threadIdx.x;
    if (i >= NSAMP) return;
    atomicAdd(&counts[cellkey(x[3*i], x[3*i+1], x[3*i+2])], 1u);
}

// ---------------- K2: scan (1 block, 1024 threads) ----------------
__global__ __launch_bounds__(1024) void scan_k(const uint* __restrict__ counts, uint* __restrict__ offs){
    __shared__ uint ps[1024];
    const int t = threadIdx.x;
    uint loc[32]; uint s = 0;
    #pragma unroll
    for (int i=0;i<32;++i){ loc[i] = counts[t*32+i]; s += loc[i]; }
    ps[t] = s; __syncthreads();
    for (int off=1; off<1024; off<<=1){
        uint v = (t>=off) ? ps[t-off] : 0u;
        __syncthreads();
        ps[t] += v;
        __syncthreads();
    }
    uint base = ps[t] - s;     // exclusive prefix
    #pragma unroll
    for (int i=0;i<32;++i){ offs[t*32+i] = base; base += loc[i]; }
}

// ---------------- K3: merged {transpose | prep_weights | PE(d) table | scatter} ----------------
__global__ __launch_bounds__(256) void prepass_k(const float* __restrict__ feat,
                                                 const float* __restrict__ W0,
                                                 const float* __restrict__ W1,
                                                 const float* __restrict__ W2,
                                                 const float* __restrict__ b0,
                                                 const float* __restrict__ b1,
                                                 const float* __restrict__ b2,
                                                 const float* __restrict__ d,
                                                 const float* __restrict__ x,
                                                 uint* __restrict__ offs,
                                                 unsigned short* __restrict__ featT,
                                                 unsigned short* __restrict__ wp,
                                                 unsigned short* __restrict__ ped,
                                                 float4* __restrict__ xs){
    const int bid = blockIdx.x, tid = threadIdx.x;
    if (bid < TRS_BLKS){
        // ---- transpose feat (3,48,512,512) fp32 -> (3,512,512,48) fp16 ----
        __shared__ unsigned short lb[256*50];
        const int pos = bid*256 + tid;
        const int p  = pos >> 18;
        const int yx = pos & (NPLANE-1);
        const float* src = feat + (size_t)p*48*NPLANE + yx;
        #pragma unroll 4
        for (int c = 0; c < 48; ++c){
            lb[tid*50 + c] = f16u(src[(size_t)c*NPLANE]);
        }
        __syncthreads();
        uint4* dst = (uint4*)(featT + (size_t)bid*(256*48));
        #pragma unroll
        for (int m = 0; m < 6; ++m){
            const int u4 = tid + m*256;
            const int byteoff = u4*16;
            const int smp = byteoff/96;
            const int off = (byteoff%96) >> 2;
            const uint* rw = (const uint*)(lb + smp*50);
            uint4 val; val.x = rw[off]; val.y = rw[off+1]; val.z = rw[off+2]; val.w = rw[off+3];
            dst[u4] = val;
        }
        return;
    }
    if (bid < TRS_BLKS + PREP_BLKS){
        // ---- weights -> fragment-packed fp16, bias folded as row K ----
        const int idx = (bid - TRS_BLKS)*256 + tid;
        if (idx >= 3*PW_LAYER) return;
        const int L = idx / PW_LAYER, base = idx % PW_LAYER;
        const float* W = (L==0)? W0 : (L==1)? W1 : W2;
        const float* B = (L==0)? b0 : (L==1)? b1 : b2;
        const int KREAL = (L==0)? 138 : 128;
        const int e  = base & 7;
        const int l  = (base >> 3) & 63;
        const int fr = base >> 9;
        const int ks = fr >> 2, nt = fr & 3;
        const int k  = ks*16 + (l >> 5)*8 + e;
        const int n  = nt*32 + (l & 31);
        float v = 0.f;
        if (k < KREAL) v = W[k*128 + n];
        else if (k == KREAL) v = B[n];
        wp[idx] = f16u(v);
        return;
    }
    if (bid < TRS_BLKS + PREP_BLKS + PED_BLKS){
        // ---- PE(d) table: ray -> 27 fp16 (stride 28) ----
        const int ray = (bid - TRS_BLKS - PREP_BLKS)*256 + tid;
        if (ray >= NRAY) return;
        const float dv0 = d[ray*3], dv1 = d[ray*3+1], dv2 = d[ray*3+2];
        unsigned short* row = ped + ray*28;
        row[0]=f16u(dv0); row[1]=f16u(dv1); row[2]=f16u(dv2);
        #pragma unroll
        for (int l=0;l<4;++l){
            const float sc = (float)(1<<l);
            float sv, cv;
            __sincosf(dv0*sc, &sv, &cv); row[3+l*6+0]=f16u(sv); row[3+l*6+3]=f16u(cv);
            __sincosf(dv1*sc, &sv, &cv); row[3+l*6+1]=f16u(sv); row[3+l*6+4]=f16u(cv);
            __sincosf(dv2*sc, &sv, &cv); row[3+l*6+2]=f16u(sv); row[3+l*6+5]=f16u(cv);
        }
        row[27] = 0;
        return;
    }
    {
        // ---- scatter (hidden under transpose) ----
        const int i = (bid - TRS_BLKS - PREP_BLKS - PED_BLKS)*256 + tid;
        if (i >= NSAMP) return;
        const float x0 = x[3*i], x1 = x[3*i+1], x2 = x[3*i+2];
        const uint pos = atomicAdd(&offs[cellkey(x0,x1,x2)], 1u);
        xs[pos] = make_float4(x0, x1, x2, __int_as_float(i));
    }
}

// ---- N-split/4 MLP layer: wave w computes cols [w*32, w*32+32) for ALL 64 samples ----
// acc[2] = 32 AGPR/wave; 9 B-loads (9KB) per layer per wave. Barriers handle in-place hazard.
__device__ __forceinline__ void run_layer_ns4(unsigned short* H, const unsigned short* __restrict__ Wp,
                                              int lane, int ln31, int kg, int wid, const int* pr){
    const unsigned short* Hrow0 = H + ln31*HSTR;
    const unsigned short* Hrow1 = H + (32+ln31)*HSTR;
    f32x16 acc0=(f32x16)0.f, acc1=(f32x16)0.f;
    // chunk A: ks 0..4
    {
        half8 bf[5];
        #pragma unroll
        for (int i=0;i<5;++i)
            bf[i] = *reinterpret_cast<const half8*>(Wp + (((i*4+wid)*64 + lane) << 3));
        #pragma unroll
        for (int ks=0; ks<5; ++ks){
            const half8 a0 = *reinterpret_cast<const half8*>(Hrow0 + ks*16 + kg*8);
            const half8 a1 = *reinterpret_cast<const half8*>(Hrow1 + ks*16 + kg*8);
            acc0 = mfma16_(a0, bf[ks], acc0);
            acc1 = mfma16_(a1, bf[ks], acc1);
        }
    }
    // chunk B: ks 5..8
    {
        half8 bf[4];
        #pragma unroll
        for (int i=0;i<4;++i)
            bf[i] = *reinterpret_cast<const half8*>(Wp + ((((5+i)*4+wid)*64 + lane) << 3));
        #pragma unroll
        for (int ks=5; ks<9; ++ks){
            const half8 a0 = *reinterpret_cast<const half8*>(Hrow0 + ks*16 + kg*8);
            const half8 a1 = *reinterpret_cast<const half8*>(Hrow1 + ks*16 + kg*8);
            acc0 = mfma16_(a0, bf[ks-5], acc0);
            acc1 = mfma16_(a1, bf[ks-5], acc1);
        }
    }
    __syncthreads();   // all waves done reading H
    #pragma unroll
    for (int r=0;r<16;++r){
        const int row = pr[r] >> 8;
        const int col = wid*32 + (pr[r] & 255);
        H[row*HSTR + col]      = f16u(fmaxf(acc0[r], 0.f));
        H[(row+32)*HSTR + col] = f16u(fmaxf(acc1[r], 0.f));
    }
    __syncthreads();   // writes visible before next layer reads
}

// ---------------- K4: fused kernel, 4 waves cooperating on 64 sorted samples ----------------
__global__ __launch_bounds__(256, 5) void nerf_mfma(
    const unsigned short* __restrict__ featT,
    const unsigned short* __restrict__ wp0, const unsigned short* __restrict__ wp1,
    const unsigned short* __restrict__ wp2,
    const float* __restrict__ W3, const float* __restrict__ b3,
    const float4* __restrict__ xs, const unsigned short* __restrict__ ped,
    float* __restrict__ out)
{
    __shared__ unsigned short H[64*HSTR];    // 18432 B, shared across 4 waves
    __shared__ uint sW3u[256];               // W3 fp16 pairs: 1024 B
    __shared__ float4 sX[64];                // 1024 B  -> total 20480 B exactly

    const int tid  = threadIdx.x;
    const int wid  = tid >> 6, lane = tid & 63;
    const int ln31 = lane & 31, kg = lane >> 5;
    const int gbase = (((int)blockIdx.x & 7)*1024 + ((int)blockIdx.x >> 3))*64;  // XCD-contiguous

    // ---- layout probes (register-only, f16 MFMA; all waves identical) ----
    half8 pa = (half8)0, pb = (half8)0, qa = (half8)0, qb = (half8)0;
    if (kg == 0){
        pa[0] = (_Float16)(float)ln31;
        pb[0] = (_Float16)1.0f;
        qa[0] = (_Float16)1.0f;
        qb[0] = (_Float16)(float)ln31;
    }
    const f32x16 zz = (f32x16)0.f;
    const f32x16 D1 = mfma16_(pa, pb, zz);
    const f32x16 D2 = mfma16_(qa, qb, zz);
    int pr[16];
    #pragma unroll
    for (int r=0;r<16;++r) pr[r] = (((int)D1[r]) << 8) | (int)D2[r];

    // ---- stage sample records + W3 ----
    if (tid < 64) sX[tid] = xs[gbase + tid];
    {
        const int k = tid >> 1, c = tid & 1;
        sW3u[tid] = ((uint)f16u(W3[k*4 + 2*c])) | (((uint)f16u(W3[k*4 + 2*c + 1])) << 16);
    }
    __syncthreads();   // sX visible to all waves

    // ---- PE(x,10): 192 units (sample, component) over 256 threads ----
    if (tid < 192){
        const int s32 = tid & 63, m = tid >> 6;   // m in 0..2
        const float4 xr = sX[s32];
        const float xn = ((m==0)? xr.x : (m==1)? xr.y : xr.z) * (1.0f/3.0f);
        unsigned short* row = H + s32*HSTR;
        row[75+m] = f16u(xn);
        float sv, cv;
        __sincosf(xn, &sv, &cv);
        #pragma unroll
        for (int l=0;l<10;++l){
            row[78+l*6+m]   = f16u(sv);
            row[78+l*6+3+m] = f16u(cv);
            const float s2v = 2.0f*sv*cv;
            const float c2v = 1.0f - 2.0f*sv*sv;
            sv = s2v; cv = c2v;
        }
    }

    // ---- PE(d): 128 units (sample, half) ----
    if (tid < 128){
        const int s32 = tid >> 1, hf = tid & 1;
        const int sid = __float_as_int(sX[s32].w);
        const uint* src = (const uint*)(ped + (sid >> 7)*28) + hf*7;
        uint* dstu = (uint*)(H + s32*HSTR + 48) + hf*7;
        if (hf == 0){
            #pragma unroll
            for (int i=0;i<7;++i) dstu[i] = src[i];
        } else {
            #pragma unroll
            for (int i=0;i<6;++i) dstu[i] = src[i];
            H[s32*HSTR + 74] = ((const unsigned short*)src)[12];
        }
    }

    // pad cols 138..143: col138 = fp16 1.0 (bias slot for L0), rest 0
    if (tid < 64){
        *(uint*)(H + tid*HSTR + 138)  = 0x00003C00u;
        *(uint2*)(H + tid*HSTR + 140) = make_uint2(0u, 0u);
    }

    // ---- gather -> cols [0..47]; 384 units over 256 threads (1.5 rounds) ----
    #pragma unroll
    for (int rr=0; rr<2; ++rr){
        const int u = rr*256 + tid;
        if (rr == 1 && tid >= 128) break;     // units 0..383
        const int s32 = u/6, ch = u - s32*6;
        const float4 xr = sX[s32];
        const float xn0 = xr.x*(1.0f/3.0f);
        const float xn1 = xr.y*(1.0f/3.0f);
        const float xn2 = xr.z*(1.0f/3.0f);
        const int c0 = ch*8;
        __half2 acc[4];
        #pragma unroll
        for (int q=0;q<4;++q) acc[q] = __float2half2_rn(0.f);
        #pragma unroll
        for (int p=0;p<3;++p){
            const float gx = (p==1)? xn1 : xn0;
            const float gy = (p==0)? xn1 : xn2;
            const float ix = ((gx+1.0f)*0.5f)*511.0f;
            const float iy = ((gy+1.0f)*0.5f)*511.0f;
            const float fx0 = floorf(ix), fy0 = floorf(iy);
            const float wx1 = ix - fx0, wy1 = iy - fy0;
            const float wx0 = 1.0f-wx1, wy0 = 1.0f-wy1;
            const int x0i = (int)fx0, y0i = (int)fy0;
            const int x0c = min(max(x0i,0),511),   x1c = min(max(x0i+1,0),511);
            const int y0c = min(max(y0i,0),511),   y1c = min(max(y0i+1,0),511);
            const uint r0 = (uint)(p*NPLANE + y0c*512);
            const uint r1 = (uint)(p*NPLANE + y1c*512);
            const uint  av[4] = {(r0+x0c)*48u, (r0+x1c)*48u, (r1+x0c)*48u, (r1+x1c)*48u};
            const float wv[4] = {wx0*wy0, wx1*wy0, wx0*wy1, wx1*wy1};
            #pragma unroll
            for (int cr=0;cr<4;++cr){
                const uint4 uv = *(const uint4*)(featT + av[cr] + c0);
                const __half2 w2 = __float2half2_rn(wv[cr]);
                union { uint4 v; __half2 h[4]; } t; t.v = uv;
                acc[0] = __hfma2(t.h[0], w2, acc[0]);
                acc[1] = __hfma2(t.h[1], w2, acc[1]);
                acc[2] = __hfma2(t.h[2], w2, acc[2]);
                acc[3] = __hfma2(t.h[3], w2, acc[3]);
            }
        }
        union { __half2 h[4]; uint4 v; } pk;
        #pragma unroll
        for (int q=0;q<4;++q) pk.h[q] = acc[q];
        *(uint4*)(H + s32*HSTR + c0) = pk.v;
    }
    __syncthreads();   // H fully built

    // ---- MLP: N-split/4 layers ----
    run_layer_ns4(H, wp0, lane, ln31, kg, wid, pr);
    // pad rewrite for L1/L2 bias slot: cols 128..143 <- [1, 0...], rows 0..63 over 128 threads
    if (tid < 128){
        const int row = tid & 63, hf = tid >> 6;
        if (hf == 0) *(uint4*)(H + row*HSTR + 128) = make_uint4(0x00003C00u,0u,0u,0u);
        else         *(uint4*)(H + row*HSTR + 136) = make_uint4(0u,0u,0u,0u);
    }
    __syncthreads();
    run_layer_ns4(H, wp1, lane, ln31, kg, wid, pr);
    run_layer_ns4(H, wp2, lane, ln31, kg, wid, pr);

    // ---- final layer 128->4 (fp16 W3 pairs from LDS); 128 units ----
    if (tid < 128){
        const int s32 = tid >> 1, cp = tid & 1;
        const unsigned short* hrow = H + s32*HSTR;
        const int sid = __float_as_int(sX[s32].w);
        const int jp = 2*cp;
        const float2 b3v = *(const float2*)(b3 + jp);
        float a0 = b3v.x, a1 = b3v.y;
        #pragma unroll
        for (int q=0;q<16;++q){
            union { uint4 v; __half2 h[4]; } u;
            u.v = *(const uint4*)(hrow + q*8);
            const int k = q*8;
            #pragma unroll
            for (int j2=0;j2<4;++j2){
                const float2 f = __half22float2(u.h[j2]);
                const int k2 = k + j2*2;
                union { uint u32; __half2 h; } w0c, w1c;
                w0c.u32 = sW3u[(k2+0)*2+cp];
                w1c.u32 = sW3u[(k2+1)*2+cp];
                const float2 w0f = __half22float2(w0c.h);
                const float2 w1f = __half22float2(w1c.h);
                a0 += f.x*w0f.x + f.y*w1f.x;
                a1 += f.x*w0f.y + f.y*w1f.y;
            }
        }
        if (cp == 1) a1 = fmaxf(a1, 0.f);
        float2 o; o.x = a0; o.y = a1;
        *(float2*)(out + (size_t)sid*4 + jp) = o;
    }
}

// ================= fallback (round-2 kernel, channel-major gather, fp32 MLP) =================
#define STR 148
#define SBLK 64
template<int K4, int KTAIL>
__device__ __forceinline__ void mlp_layer_fb(float (*Hs)[STR], const float* __restrict__ W,
                                             const float* __restrict__ B, int tid){
    const int tx = tid & 31, ty = tid >> 5;
    const int s0 = ty*8, j0 = tx*4;
    float acc[8][4];
    #pragma unroll
    for (int i=0;i<8;++i){ acc[i][0]=0.f; acc[i][1]=0.f; acc[i][2]=0.f; acc[i][3]=0.f; }
    for (int kk = 0; kk < K4; ++kk){
        const int k = kk*4;
        const float4 wa = *(const float4*)(W + (size_t)(k+0)*128 + j0);
        const float4 wb = *(const float4*)(W + (size_t)(k+1)*128 + j0);
        const float4 wc = *(const float4*)(W + (size_t)(k+2)*128 + j0);
        const float4 wd = *(const float4*)(W + (size_t)(k+3)*128 + j0);
        #pragma unroll
        for (int i=0;i<8;++i){
            const float4 h = *(const float4*)&Hs[s0+i][k];
            acc[i][0] += h.x*wa.x + h.y*wb.x + h.z*wc.x + h.w*wd.x;
            acc[i][1] += h.x*wa.y + h.y*wb.y + h.z*wc.y + h.w*wd.y;
            acc[i][2] += h.x*wa.z + h.y*wb.z + h.z*wc.z + h.w*wd.z;
            acc[i][3] += h.x*wa.w + h.y*wb.w + h.z*wc.w + h.w*wd.w;
        }
    }
    #pragma unroll
    for (int t=0;t<KTAIL;++t){
        const int k = K4*4+t;
        const float4 wa = *(const float4*)(W + (size_t)k*128 + j0);
        #pragma unroll
        for (int i=0;i<8;++i){
            const float h = Hs[s0+i][k];
            acc[i][0] += h*wa.x; acc[i][1] += h*wa.y; acc[i][2] += h*wa.z; acc[i][3] += h*wa.w;
        }
    }
    const float4 bb = *(const float4*)(B + j0);
    __syncthreads();
    #pragma unroll
    for (int i=0;i<8;++i){
        float4 o;
        o.x = fmaxf(acc[i][0]+bb.x, 0.f);
        o.y = fmaxf(acc[i][1]+bb.y, 0.f);
        o.z = fmaxf(acc[i][2]+bb.z, 0.f);
        o.w = fmaxf(acc[i][3]+bb.w, 0.f);
        *(float4*)&Hs[s0+i][j0] = o;
    }
    __syncthreads();
}

__global__ __launch_bounds__(256) void nerf_fused_fb(
    const float* __restrict__ x, const float* __restrict__ d,
    const float* __restrict__ feat,
    const float* __restrict__ W0, const float* __restrict__ b0,
    const float* __restrict__ W1, const float* __restrict__ b1,
    const float* __restrict__ W2, const float* __restrict__ b2,
    const float* __restrict__ W3, const float* __restrict__ b3,
    float* __restrict__ out)
{
    __shared__ float Hs[SBLK][STR];
    __shared__ uint4  sA[3][SBLK];
    __shared__ float4 sW[3][SBLK];

    const int tid = threadIdx.x;
    const int g0 = blockIdx.x * SBLK;

    if (tid < 192){
        const int s = tid & 63, p = tid >> 6;
        const int g = g0 + s;
        const float xn0 = x[3*g+0]/3.0f, xn1 = x[3*g+1]/3.0f, xn2 = x[3*g+2]/3.0f;
        const float gx = (p==1)? xn1 : xn0;
        const float gy = (p==0)? xn1 : xn2;
        const float ix = ((gx+1.0f)*0.5f)*511.0f;
        const float iy = ((gy+1.0f)*0.5f)*511.0f;
        const float fx0 = floorf(ix), fy0 = floorf(iy);
        const float wx1 = ix - fx0, wy1 = iy - fy0;
        const float wx0 = 1.0f-wx1, wy0 = 1.0f-wy1;
        const int x0i = (int)fx0, y0i = (int)fy0;
        const int x0c = min(max(x0i,0),511),   x1c = min(max(x0i+1,0),511);
        const int y0c = min(max(y0i,0),511),   y1c = min(max(y0i+1,0),511);
        const uint bp = (uint)p*48u*NPLANE;
        sA[p][s] = make_uint4(bp + y0c*512 + x0c, bp + y0c*512 + x1c,
                              bp + y1c*512 + x0c, bp + y1c*512 + x1c);
        sW[p][s] = make_float4(wx0*wy0, wx1*wy0, wx0*wy1, wx1*wy1);
    }
    if (tid < 64){
        const int s = tid, g = g0 + s;
        float xn[3];
        xn[0]=x[3*g+0]/3.0f; xn[1]=x[3*g+1]/3.0f; xn[2]=x[3*g+2]/3.0f;
        Hs[s][75]=xn[0]; Hs[s][76]=xn[1]; Hs[s][77]=xn[2];
        float f = 1.0f;
        for (int l=0;l<10;++l){
            #pragma unroll
            for (int m=0;m<3;++m){
                const float a = xn[m]*f;
                Hs[s][78+l*6+m]   = sinf(a);
                Hs[s][78+l*6+3+m] = cosf(a);
            }
            f *= 2.0f;
        }
    } else if (tid < 91){
        const int k = tid-64;
        const int ray = g0 >> 7;
        float v;
        if (k < 3) v = d[ray*3+k];
        else {
            const int l=(k-3)/6, r=(k-3)%6;
            const float a = d[ray*3 + (r%3)] * (float)(1<<l);
            v = (r<3)? sinf(a) : cosf(a);
        }
        for (int s2=0;s2<64;++s2) Hs[s2][48+k]=v;
    }
    __syncthreads();

    for (int it = tid; it < 384; it += 256){
        const int s = it & 63;
        const int c0 = (it >> 6)*8;
        float acc[8];
        #pragma unroll
        for (int q=0;q<8;++q) acc[q]=0.f;
        #pragma unroll
        for (int p=0;p<3;++p){
            const uint4  aa = sA[p][s];
            const float4 ww = sW[p][s];
            const uint  av[4] = {aa.x,aa.y,aa.z,aa.w};
            const float wv[4] = {ww.x,ww.y,ww.z,ww.w};
            #pragma unroll
            for (int cr=0;cr<4;++cr){
                const float w = wv[cr];
                const float* bsrc = feat + av[cr] + (size_t)c0*NPLANE;
                #pragma unroll
                for (int q=0;q<8;++q) acc[q] += w*bsrc[(size_t)q*NPLANE];
            }
        }
        *(float4*)&Hs[s][c0]   = make_float4(acc[0],acc[1],acc[2],acc[3]);
        *(float4*)&Hs[s][c0+4] = make_float4(acc[4],acc[5],acc[6],acc[7]);
    }
    __syncthreads();

    mlp_layer_fb<34,2>(Hs, W0, b0, tid);
    mlp_layer_fb<32,0>(Hs, W1, b1, tid);
    mlp_layer_fb<32,0>(Hs, W2, b2, tid);

    {
        const int s = tid>>2, j = tid&3;
        float acc = 0.f;
        for (int kk=0; kk<32; ++kk){
            const float4 h = *(const float4*)&Hs[s][kk*4];
            const int k = kk*4;
            acc += h.x*W3[(k+0)*4+j] + h.y*W3[(k+1)*4+j]
                 + h.z*W3[(k+2)*4+j] + h.w*W3[(k+3)*4+j];
        }
        acc += b3[j];
        if (j==3) acc = fmaxf(acc, 0.f);
        out[(size_t)blockIdx.x*256 + tid] = acc;
    }
}

extern "C" void kernel_launch(void* const* d_in, const int* in_sizes, int n_in,
                              void* d_out, int out_size, void* d_ws, size_t ws_size,
                              hipStream_t stream){
    (void)in_sizes; (void)n_in; (void)out_size;
    const float* x    = (const float*)d_in[0];
    const float* ddir = (const float*)d_in[1];
    const float* feat = (const float*)d_in[2];
    const float* W0 = (const float*)d_in[3];  const float* b0 = (const float*)d_in[4];
    const float* W1 = (const float*)d_in[5];  const float* b1 = (const float*)d_in[6];
    const float* W2 = (const float*)d_in[7];  const float* b2 = (const float*)d_in[8];
    const float* W3 = (const float*)d_in[9];  const float* b3 = (const float*)d_in[10];
    float* out = (float*)d_out;

    char* wsb = (char*)d_ws;

    if (ws_size >= WS_END){
        unsigned short* wsu   = (unsigned short*)wsb;
        unsigned short* featT = (unsigned short*)(wsb + WS_FEAT_OFF);
        uint*   counts = (uint*)(wsb + WS_CNT_OFF);
        uint*   offs   = (uint*)(wsb + WS_OFFS_OFF);
        float4* xsrec  = (float4*)(wsb + WS_XS_OFF);
        unsigned short* ped = (unsigned short*)(wsb + WS_PED_OFF);
        hipMemsetAsync(counts, 0, NCELL*sizeof(uint), stream);
        hist_k<<<2048, 256, 0, stream>>>(x, counts);
        scan_k<<<1, 1024, 0, stream>>>(counts, offs);
        prepass_k<<<K2_BLKS, 256, 0, stream>>>(feat, W0, W1, W2, b0, b1, b2, ddir, x,
                                               offs, featT, wsu, ped, xsrec);
        nerf_mfma<<<8192, 256, 0, stream>>>(featT,
                                            wsu, wsu + PW_LAYER, wsu + 2*PW_LAYER,
                                            W3, b3, xsrec, ped, out);
    } else {
        nerf_fused_fb<<<8192, 256, 0, stream>>>(x, ddir, feat,
                                                W0,b0,W1,b1,W2,b2,W3,b3, out);
    }
}